// Round 1
// baseline (98.897 us; speedup 1.0000x reference)
//
#include <hip/hip_runtime.h>
#include <cfloat>

#define NEG_INF_F (-1e30f)

// ---------------- Kernel 1: QA-head GEMV + masking ----------------
// One wave (64 lanes) per (b,s) row. Row = 1024 f32 = 4 KB, read as 4
// contiguous float4 passes per wave (fully coalesced, 1 KiB/inst).
__global__ __launch_bounds__(256) void qa_logits_kernel(
    const float* __restrict__ X,     // (B*S, H)
    const float* __restrict__ mask,  // (B*S)
    const float* __restrict__ W,     // (H, 2) row-major
    const float* __restrict__ bqa,   // (2)
    float* __restrict__ out,         // [0,total): start, [total,2*total): end
    int total, int H) {
  int wave = (int)((blockIdx.x * (size_t)blockDim.x + threadIdx.x) >> 6);
  int lane = threadIdx.x & 63;
  if (wave >= total) return;
  const float* row = X + (size_t)wave * H;
  float s0 = 0.f, s1 = 0.f;
  int iters = H >> 8;  // 256 floats per wave-pass
  for (int k = 0; k < iters; ++k) {
    int h = (k * 64 + lane) * 4;
    const float4 x   = *reinterpret_cast<const float4*>(row + h);
    const float4 w01 = *reinterpret_cast<const float4*>(W + 2 * h);      // rows h,h+1
    const float4 w23 = *reinterpret_cast<const float4*>(W + 2 * h + 4);  // rows h+2,h+3
    s0 += x.x * w01.x + x.y * w01.z + x.z * w23.x + x.w * w23.z;
    s1 += x.x * w01.y + x.y * w01.w + x.z * w23.y + x.w * w23.w;
  }
#pragma unroll
  for (int off = 32; off > 0; off >>= 1) {
    s0 += __shfl_down(s0, off);
    s1 += __shfl_down(s1, off);
  }
  if (lane == 0) {
    float m = mask[wave];
    float inv = 1.f - m;
    out[wave]         = (s0 + bqa[0]) * m + inv * NEG_INF_F;
    out[total + wave] = (s1 + bqa[1]) * m + inv * NEG_INF_F;
  }
}

// ---------------- Kernel 2: banded top-5 span search ----------------
// Valid spans: i in [4,S) with j in [i, i+30) ∩ [0,S), plus (1,1),(2,2),(3,3).
// Everything else is -1e30 in the reference and can never enter top-5 here.

__device__ __forceinline__ bool t5_better(float av, int ai, float bv, int bi) {
  // jax top_k tie-break: lower flat index wins on equal value
  return av > bv || (av == bv && ai < bi);
}

// Sorted-descending 5-list insert; all indices compile-time (no scratch).
__device__ __forceinline__ void t5_insert(float v[5], int id[5], float nv, int ni) {
  if (!t5_better(nv, ni, v[4], id[4])) return;
  v[4] = nv; id[4] = ni;
#pragma unroll
  for (int q = 4; q > 0; --q) {
    if (t5_better(v[q], id[q], v[q - 1], id[q - 1])) {
      float tv = v[q]; v[q] = v[q - 1]; v[q - 1] = tv;
      int ti = id[q]; id[q] = id[q - 1]; id[q - 1] = ti;
    }
  }
}

#define TPB2 512

__global__ __launch_bounds__(TPB2) void topk_kernel(
    const float* __restrict__ logits,  // kernel-1 output (start then end)
    float* __restrict__ out,           // full d_out
    int B, int S, int max_len) {
  int b = blockIdx.x;
  const float* st = logits + (size_t)b * S;
  const float* en = logits + (size_t)(B + b) * S;

  float v[5]; int id[5];
#pragma unroll
  for (int q = 0; q < 5; ++q) { v[q] = -FLT_MAX; id[q] = 0x7fffffff; }

  for (int i = 4 + (int)threadIdx.x; i < S; i += TPB2) {
    float si = st[i];
    int jmax = min(S, i + max_len);
    for (int j = i; j < jmax; ++j) t5_insert(v, id, si + en[j], i * S + j);
  }
  if (threadIdx.x == 0) {
#pragma unroll
    for (int i = 1; i <= 3; ++i) t5_insert(v, id, st[i] + en[i], i * S + i);
  }

  // wave-level butterfly merge (insert-based: no runtime reg indexing)
  for (int off = 1; off < 64; off <<= 1) {
    float ov[5]; int oid[5];
#pragma unroll
    for (int q = 0; q < 5; ++q) {
      ov[q] = __shfl_xor(v[q], off);
      oid[q] = __shfl_xor(id[q], off);
    }
#pragma unroll
    for (int q = 0; q < 5; ++q) t5_insert(v, id, ov[q], oid[q]);
  }

  __shared__ float sv[(TPB2 / 64) * 5];
  __shared__ int   sid[(TPB2 / 64) * 5];
  int wv = threadIdx.x >> 6;
  if ((threadIdx.x & 63) == 0) {
#pragma unroll
    for (int q = 0; q < 5; ++q) { sv[wv * 5 + q] = v[q]; sid[wv * 5 + q] = id[q]; }
  }
  __syncthreads();

  if (threadIdx.x == 0) {
    for (int w = 1; w < TPB2 / 64; ++w)
      for (int q = 0; q < 5; ++q) t5_insert(v, id, sv[w * 5 + q], sid[w * 5 + q]);
    float* ts = out + 2 * (size_t)B * S;  // top_start region
    float* te = ts + (size_t)B * 5;       // top_end region
#pragma unroll
    for (int q = 0; q < 5; ++q) {
      ts[b * 5 + q] = (float)(id[q] / S);
      te[b * 5 + q] = (float)(id[q] % S);
    }
  }
}

extern "C" void kernel_launch(void* const* d_in, const int* in_sizes, int n_in,
                              void* d_out, int out_size, void* d_ws, size_t ws_size,
                              hipStream_t stream) {
  const float* X    = (const float*)d_in[0];  // (B,S,H)
  const float* mask = (const float*)d_in[1];  // (B,S)
  const float* W    = (const float*)d_in[2];  // (H,2)
  const float* bqa  = (const float*)d_in[3];  // (2)
  // d_in[4] = top_k (device); shapes fixed by setup_inputs
  const int B = 8, S = 4096, H = 1024, MAX_LEN = 30;
  const int total = B * S;
  float* out = (float*)d_out;

  // Kernel 1: one wave per row, 4 waves per 256-thread block.
  int waves_per_block = 256 / 64;
  int blocks = (total + waves_per_block - 1) / waves_per_block;
  qa_logits_kernel<<<blocks, 256, 0, stream>>>(X, mask, W, bqa, out, total, H);

  // Kernel 2: one block per batch.
  topk_kernel<<<B, TPB2, 0, stream>>>(out, out, B, S, MAX_LEN);
}

// Round 2
// 50.894 us; speedup vs baseline: 1.9432x; 1.9432x over previous
//
#include <hip/hip_runtime.h>
#include <cfloat>

#define NEG_INF_F (-1e30f)

// ---------------- Kernel 1: QA-head GEMV + masking ----------------
// One wave (64 lanes) per (b,s) row. Row = 1024 f32 = 4 KB, read as 4
// contiguous float4 passes per wave (fully coalesced, 1 KiB/inst).
__global__ __launch_bounds__(256) void qa_logits_kernel(
    const float* __restrict__ X,     // (B*S, H)
    const float* __restrict__ mask,  // (B*S)
    const float* __restrict__ W,     // (H, 2) row-major
    const float* __restrict__ bqa,   // (2)
    float* __restrict__ out,         // [0,total): start, [total,2*total): end
    int total, int H) {
  int wave = (int)((blockIdx.x * (size_t)blockDim.x + threadIdx.x) >> 6);
  int lane = threadIdx.x & 63;
  if (wave >= total) return;
  const float* row = X + (size_t)wave * H;
  float s0 = 0.f, s1 = 0.f;
  int iters = H >> 8;  // 256 floats per wave-pass
  for (int k = 0; k < iters; ++k) {
    int h = (k * 64 + lane) * 4;
    const float4 x   = *reinterpret_cast<const float4*>(row + h);
    const float4 w01 = *reinterpret_cast<const float4*>(W + 2 * h);      // rows h,h+1
    const float4 w23 = *reinterpret_cast<const float4*>(W + 2 * h + 4);  // rows h+2,h+3
    s0 += x.x * w01.x + x.y * w01.z + x.z * w23.x + x.w * w23.z;
    s1 += x.x * w01.y + x.y * w01.w + x.z * w23.y + x.w * w23.w;
  }
#pragma unroll
  for (int off = 32; off > 0; off >>= 1) {
    s0 += __shfl_down(s0, off);
    s1 += __shfl_down(s1, off);
  }
  if (lane == 0) {
    float m = mask[wave];
    float inv = 1.f - m;
    out[wave]         = (s0 + bqa[0]) * m + inv * NEG_INF_F;
    out[total + wave] = (s1 + bqa[1]) * m + inv * NEG_INF_F;
  }
}

// ---------------- Top-5 span search (two-stage) ----------------
// Valid spans: i in [4,S) with j in [i, i+30) ∩ [0,S), plus (1,1),(2,2),(3,3).
// Everything else is -1e30 in the reference and can never enter the top-5.

__device__ __forceinline__ bool t5_better(float av, int ai, float bv, int bi) {
  // jax top_k tie-break: lower flat index wins on equal value
  return av > bv || (av == bv && ai < bi);
}

// Sorted-descending 5-list insert; all indices compile-time (no scratch).
__device__ __forceinline__ void t5_insert(float v[5], int id[5], float nv, int ni) {
  if (!t5_better(nv, ni, v[4], id[4])) return;
  v[4] = nv; id[4] = ni;
#pragma unroll
  for (int q = 4; q > 0; --q) {
    if (t5_better(v[q], id[q], v[q - 1], id[q - 1])) {
      float tv = v[q]; v[q] = v[q - 1]; v[q - 1] = tv;
      int ti = id[q]; id[q] = id[q - 1]; id[q - 1] = ti;
    }
  }
}

__device__ __forceinline__ void t5_init(float v[5], int id[5]) {
#pragma unroll
  for (int q = 0; q < 5; ++q) { v[q] = -FLT_MAX; id[q] = 0x7fffffff; }
}

__device__ __forceinline__ void t5_wave_merge(float v[5], int id[5]) {
#pragma unroll
  for (int off = 1; off < 64; off <<= 1) {
    float ov[5]; int oid[5];
#pragma unroll
    for (int q = 0; q < 5; ++q) {
      ov[q] = __shfl_xor(v[q], off);
      oid[q] = __shfl_xor(id[q], off);
    }
#pragma unroll
    for (int q = 0; q < 5; ++q) t5_insert(v, id, ov[q], oid[q]);
  }
}

#define T1 256  // threads per stage-1 block; one thread per row i

// Stage 1: each block covers 256 rows of one batch; writes block top-5 to ws.
__global__ __launch_bounds__(T1) void topk_stage1(
    const float* __restrict__ logits,  // kernel-1 output (start then end)
    float* __restrict__ wv_out,        // (B*blocks_per_b, 5)
    int* __restrict__ wi_out,
    int B, int S, int max_len, int blocks_per_b) {
  int b  = blockIdx.x / blocks_per_b;
  int rb = blockIdx.x % blocks_per_b;
  int i  = rb * T1 + (int)threadIdx.x;
  const float* st = logits + (size_t)b * S;
  const float* en = logits + (size_t)(B + b) * S;

  float v[5]; int id[5];
  t5_init(v, id);

  if (i < S) {
    if (i >= 4) {
      float si = st[i];
      int jmax = min(S, i + max_len);
#pragma unroll 6
      for (int j = i; j < jmax; ++j) t5_insert(v, id, si + en[j], i * S + j);
    } else if (i >= 1) {
      t5_insert(v, id, st[i] + en[i], i * S + i);  // (1,1),(2,2),(3,3)
    }
  }

  t5_wave_merge(v, id);

  __shared__ float sv[(T1 / 64) * 5];
  __shared__ int   sid[(T1 / 64) * 5];
  int wv = threadIdx.x >> 6;
  if ((threadIdx.x & 63) == 0) {
#pragma unroll
    for (int q = 0; q < 5; ++q) { sv[wv * 5 + q] = v[q]; sid[wv * 5 + q] = id[q]; }
  }
  __syncthreads();
  if (threadIdx.x == 0) {
    for (int w = 1; w < T1 / 64; ++w)
#pragma unroll
      for (int q = 0; q < 5; ++q) t5_insert(v, id, sv[w * 5 + q], sid[w * 5 + q]);
    float* ov = wv_out + (size_t)blockIdx.x * 5;
    int*   oi = wi_out + (size_t)blockIdx.x * 5;
#pragma unroll
    for (int q = 0; q < 5; ++q) { ov[q] = v[q]; oi[q] = id[q]; }
  }
}

// Stage 2: one wave per batch merges blocks_per_b*5 candidates.
__global__ __launch_bounds__(64) void topk_stage2(
    const float* __restrict__ wv_in, const int* __restrict__ wi_in,
    float* __restrict__ out, int B, int S, int blocks_per_b) {
  int b = blockIdx.x;
  int lane = threadIdx.x;
  int n = blocks_per_b * 5;
  float v[5]; int id[5];
  t5_init(v, id);
  for (int c = lane; c < n; c += 64)
    t5_insert(v, id, wv_in[(size_t)b * n + c], wi_in[(size_t)b * n + c]);
  t5_wave_merge(v, id);
  if (lane == 0) {
    float* ts = out + 2 * (size_t)B * S;  // top_start region
    float* te = ts + (size_t)B * 5;       // top_end region
#pragma unroll
    for (int q = 0; q < 5; ++q) {
      ts[b * 5 + q] = (float)(id[q] / S);
      te[b * 5 + q] = (float)(id[q] % S);
    }
  }
}

extern "C" void kernel_launch(void* const* d_in, const int* in_sizes, int n_in,
                              void* d_out, int out_size, void* d_ws, size_t ws_size,
                              hipStream_t stream) {
  const float* X    = (const float*)d_in[0];  // (B,S,H)
  const float* mask = (const float*)d_in[1];  // (B,S)
  const float* W    = (const float*)d_in[2];  // (H,2)
  const float* bqa  = (const float*)d_in[3];  // (2)
  const int B = 8, S = 4096, H = 1024, MAX_LEN = 30;
  const int total = B * S;
  float* out = (float*)d_out;

  // Kernel 1: one wave per row, 4 waves per 256-thread block.
  int waves_per_block = 256 / 64;
  int blocks = (total + waves_per_block - 1) / waves_per_block;
  qa_logits_kernel<<<blocks, 256, 0, stream>>>(X, mask, W, bqa, out, total, H);

  // Two-stage top-k.
  const int blocks_per_b = (S + T1 - 1) / T1;  // 16
  float* wv_ws = (float*)d_ws;
  int*   wi_ws = (int*)((char*)d_ws + (size_t)B * blocks_per_b * 5 * sizeof(float));
  topk_stage1<<<B * blocks_per_b, T1, 0, stream>>>(out, wv_ws, wi_ws, B, S, MAX_LEN, blocks_per_b);
  topk_stage2<<<B, 64, 0, stream>>>(wv_ws, wi_ws, out, B, S, blocks_per_b);
}

// Round 3
// 41.771 us; speedup vs baseline: 2.3676x; 1.2184x over previous
//
#include <hip/hip_runtime.h>
#include <cfloat>

#define NEG_INF_F (-1e30f)

// ---------------- Kernel 1: QA-head GEMV + masking ----------------
// One wave (64 lanes) per (b,s) row. Row = 1024 f32 = 4 KB, read as 4
// contiguous float4 passes per wave (fully coalesced, 1 KiB/inst).
// Memory-bound: 134 MB of X at ~6.7 TB/s ≈ 20 us (measured round 1-2).
__global__ __launch_bounds__(256) void qa_logits_kernel(
    const float* __restrict__ X,     // (B*S, H)
    const float* __restrict__ mask,  // (B*S)
    const float* __restrict__ W,     // (H, 2) row-major
    const float* __restrict__ bqa,   // (2)
    float* __restrict__ out,         // [0,total): start, [total,2*total): end
    int total, int H) {
  int wave = (int)((blockIdx.x * (size_t)blockDim.x + threadIdx.x) >> 6);
  int lane = threadIdx.x & 63;
  if (wave >= total) return;
  const float* row = X + (size_t)wave * H;
  float s0 = 0.f, s1 = 0.f;
  int iters = H >> 8;  // 256 floats per wave-pass
  for (int k = 0; k < iters; ++k) {
    int h = (k * 64 + lane) * 4;
    const float4 x   = *reinterpret_cast<const float4*>(row + h);
    const float4 w01 = *reinterpret_cast<const float4*>(W + 2 * h);      // rows h,h+1
    const float4 w23 = *reinterpret_cast<const float4*>(W + 2 * h + 4);  // rows h+2,h+3
    s0 += x.x * w01.x + x.y * w01.z + x.z * w23.x + x.w * w23.z;
    s1 += x.x * w01.y + x.y * w01.w + x.z * w23.y + x.w * w23.w;
  }
#pragma unroll
  for (int off = 32; off > 0; off >>= 1) {
    s0 += __shfl_down(s0, off);
    s1 += __shfl_down(s1, off);
  }
  if (lane == 0) {
    float m = mask[wave];
    float inv = 1.f - m;
    out[wave]         = (s0 + bqa[0]) * m + inv * NEG_INF_F;
    out[total + wave] = (s1 + bqa[1]) * m + inv * NEG_INF_F;
  }
}

// ---------------- Top-5 span search (two-stage) ----------------
// Valid spans: i in [4,S) with j in [i, i+30) ∩ [0,S), plus (1,1),(2,2),(3,3).
// Everything else is -1e30 in the reference and can never enter the top-5
// (here ans_mask==1 so real candidates are ~O(100) >> -1e30).

__device__ __forceinline__ bool t5_better(float av, int ai, float bv, int bi) {
  // jax top_k tie-break: lower flat index wins on equal value
  return av > bv || (av == bv && ai < bi);
}

// Sorted-descending 5-list insert; all indices compile-time (no scratch).
__device__ __forceinline__ void t5_insert(float v[5], int id[5], float nv, int ni) {
  if (!t5_better(nv, ni, v[4], id[4])) return;
  v[4] = nv; id[4] = ni;
#pragma unroll
  for (int q = 4; q > 0; --q) {
    if (t5_better(v[q], id[q], v[q - 1], id[q - 1])) {
      float tv = v[q]; v[q] = v[q - 1]; v[q - 1] = tv;
      int ti = id[q]; id[q] = id[q - 1]; id[q - 1] = ti;
    }
  }
}

__device__ __forceinline__ void t5_init(float v[5], int id[5]) {
#pragma unroll
  for (int q = 0; q < 5; ++q) { v[q] = -FLT_MAX; id[q] = 0x7fffffff; }
}

// Wave-wide top-5 of each lane's local sorted-5 list, via 5 argmax rounds.
// After return, rv/rid hold the wave's top-5 (same in every lane).
__device__ __forceinline__ void wave_top5(float v[5], int id[5],
                                          float rv[5], int rid[5]) {
#pragma unroll
  for (int r = 0; r < 5; ++r) {
    float bv = v[0]; int bi = id[0];
#pragma unroll
    for (int q = 1; q < 5; ++q)
      if (t5_better(v[q], id[q], bv, bi)) { bv = v[q]; bi = id[q]; }
#pragma unroll
    for (int off = 1; off < 64; off <<= 1) {
      float ov = __shfl_xor(bv, off);
      int oi = __shfl_xor(bi, off);
      if (t5_better(ov, oi, bv, bi)) { bv = ov; bi = oi; }
    }
    rv[r] = bv; rid[r] = bi;
    // invalidate winner in its owning lane (candidate ids are unique)
#pragma unroll
    for (int q = 0; q < 5; ++q)
      if (id[q] == bi) v[q] = -FLT_MAX;
  }
}

#define S1_TPB 64  // one wave per block; one row per lane

// Stage 1: block = 64 consecutive rows of one batch. Window preloaded into
// registers (loads OUT of the insert dep-chain), then 30 register inserts,
// then 5 argmax rounds. 512 blocks -> 2 blocks/CU, all CUs busy.
__global__ __launch_bounds__(S1_TPB) void topk_stage1(
    const float* __restrict__ logits,  // kernel-1 output (start then end)
    float* __restrict__ wv_out,        // (B*blocks_per_b, 5)
    int* __restrict__ wi_out,
    int B, int S, int blocks_per_b) {
  int b  = blockIdx.x / blocks_per_b;
  int rb = blockIdx.x % blocks_per_b;
  int lane = (int)threadIdx.x;
  int i = rb * S1_TPB + lane;
  const float* st = logits + (size_t)b * S;
  const float* en = logits + (size_t)(B + b) * S;

  float v[5]; int id[5];
  t5_init(v, id);

  if (i >= 4) {
    float si = st[i];
    float e[30];
#pragma unroll
    for (int c = 0; c < 30; ++c) {
      int j = i + c;
      e[c] = (j < S) ? en[j] : NEG_INF_F;  // all 30 loads issued up front
    }
    int base = i * S + i;
#pragma unroll
    for (int c = 0; c < 30; ++c) t5_insert(v, id, si + e[c], base + c);
  } else if (i >= 1) {
    t5_insert(v, id, st[i] + en[i], i * S + i);  // (1,1),(2,2),(3,3)
  }

  float rv[5]; int rid[5];
  wave_top5(v, id, rv, rid);

  if (lane == 0) {
    float* ov = wv_out + (size_t)blockIdx.x * 5;
    int*   oi = wi_out + (size_t)blockIdx.x * 5;
#pragma unroll
    for (int q = 0; q < 5; ++q) { ov[q] = rv[q]; oi[q] = rid[q]; }
  }
}

// Stage 2: one wave per batch merges blocks_per_b*5 = 320 candidates (5/lane).
__global__ __launch_bounds__(64) void topk_stage2(
    const float* __restrict__ wv_in, const int* __restrict__ wi_in,
    float* __restrict__ out, int B, int S, int blocks_per_b) {
  int b = blockIdx.x;
  int lane = (int)threadIdx.x;
  int n = blocks_per_b * 5;
  const float* wv = wv_in + (size_t)b * n;
  const int*   wi = wi_in + (size_t)b * n;

  float v[5]; int id[5];
  t5_init(v, id);
#pragma unroll 5
  for (int c = lane; c < n; c += 64)
    t5_insert(v, id, wv[c], wi[c]);

  float rv[5]; int rid[5];
  wave_top5(v, id, rv, rid);

  if (lane == 0) {
    float* ts = out + 2 * (size_t)B * S;  // top_start region
    float* te = ts + (size_t)B * 5;       // top_end region
#pragma unroll
    for (int q = 0; q < 5; ++q) {
      ts[b * 5 + q] = (float)(rid[q] / S);
      te[b * 5 + q] = (float)(rid[q] % S);
    }
  }
}

extern "C" void kernel_launch(void* const* d_in, const int* in_sizes, int n_in,
                              void* d_out, int out_size, void* d_ws, size_t ws_size,
                              hipStream_t stream) {
  const float* X    = (const float*)d_in[0];  // (B,S,H)
  const float* mask = (const float*)d_in[1];  // (B,S)
  const float* W    = (const float*)d_in[2];  // (H,2)
  const float* bqa  = (const float*)d_in[3];  // (2)
  const int B = 8, S = 4096, H = 1024;
  const int total = B * S;
  float* out = (float*)d_out;

  // Kernel 1: one wave per row, 4 waves per 256-thread block.
  int waves_per_block = 256 / 64;
  int blocks = (total + waves_per_block - 1) / waves_per_block;
  qa_logits_kernel<<<blocks, 256, 0, stream>>>(X, mask, W, bqa, out, total, H);

  // Two-stage top-k.
  const int blocks_per_b = S / S1_TPB;  // 64
  float* wv_ws = (float*)d_ws;
  int*   wi_ws = (int*)((char*)d_ws + (size_t)B * blocks_per_b * 5 * sizeof(float));
  topk_stage1<<<B * blocks_per_b, S1_TPB, 0, stream>>>(out, wv_ws, wi_ws, B, S, blocks_per_b);
  topk_stage2<<<B, 64, 0, stream>>>(wv_ws, wi_ws, out, B, S, blocks_per_b);
}